// Round 7
// baseline (351.904 us; speedup 1.0000x reference)
//
#include <hip/hip_runtime.h>
#include <hip/hip_fp16.h>

typedef _Float16 f16;
typedef _Float16 f16x8 __attribute__((ext_vector_type(8)));
typedef float f32x4 __attribute__((ext_vector_type(4)));
typedef unsigned long long ull;

#define BB 4
#define TT 16
#define HH 64
#define WW 64
#define CC 32
#define FF 64
#define GG 256  // 4F gates

__device__ __forceinline__ float hsig(float z) {
    return fminf(fmaxf(0.2f * z + 0.5f, 0.f), 1.f);
}
__device__ __forceinline__ float tanh_fast(float x) {
    return 1.f - 2.f / (__expf(2.f * x) + 1.f);
}

__device__ __forceinline__ void async_copy16(const void* g, void* l) {
    __builtin_amdgcn_global_load_lds(
        (const __attribute__((address_space(1))) unsigned*)g,
        (__attribute__((address_space(3))) unsigned*)l, 16, 0, 0);
}

// --- Weight prep: TWO layouts.
// Layout F (fused): wcatF[p][j][slot][e], p=phase(9), j=piece(12)=cw*4+quad,
//   slot = gate ^ ((j&3)<<1)  <-- bank-decorrelating XOR: the 4 quads of a wave read
//   4 distinct 16B bank-quartets instead of colliding at stride 4096B (r4's 1.46e7
//   conflicts). gate = cls*64 + fch. global_load_lds copies pieces LINEARLY, so the
//   swizzle lives entirely in global memory order (both-sides rule).
// Layout B (fallback, round-4 piece-major): wcatB[p][j][gate][e].
__global__ void wprep_kernel(const float* __restrict__ wx, const float* __restrict__ wh,
                             f16* __restrict__ wcatF, f16* __restrict__ wcatB) {
    int e0 = blockIdx.x * 256 + threadIdx.x;   // grid covers exactly 221184
    float val; int k, ng;
    if (e0 < 9 * CC * GG) {                    // Wx: e = (tap*32+c)*256 + n
        ng = e0 & 255; k = e0 >> 8; val = wx[e0];
    } else {                                   // Wh: e = (tap*64+f)*256 + n
        int e = e0 - 9 * CC * GG;
        ng = e & 255; k = 288 + (e >> 8); val = wh[e];
    }
    int p = k / 96, r = k % 96, j = r >> 3, el = r & 7;
    wcatB[((p * 12 + j) * 256 + ng) * 8 + el] = (f16)val;
    int slot = ng ^ ((j & 3) << 1);
    wcatF[((p * 12 + j) * 256 + slot) * 8 + el] = (f16)val;
}

// x staging with fused LayerNorm into the 10x10 patch (stride 72); 200 threads,
// 2 threads per pixel (16ch halves), pair-combined via lane shuffle.
__device__ __forceinline__ void stage_x_ln(const float* __restrict__ x, int bb, int t,
                                           int ty, int tx, int tid,
                                           const float* sg, const float* sb,
                                           f16* __restrict__ xpatch) {
    if (tid < 200) {
        int pix = tid >> 1, part = tid & 1;
        int py = pix / 10, px_ = pix % 10;
        int gy = ty * 8 - 1 + py, gx = tx * 8 - 1 + px_;
        if (gy >= 0 && gy < HH && gx >= 0 && gx < WW) {
            const float* xp = x + ((size_t)(bb * TT + t) * (HH * WW)
                                   + gy * WW + gx) * CC + part * 16;
            float v[16];
            float s = 0.f, s2 = 0.f;
#pragma unroll
            for (int j = 0; j < 4; j++) {
                float4 t4 = *(const float4*)(xp + j * 4);
                v[j * 4] = t4.x; v[j * 4 + 1] = t4.y; v[j * 4 + 2] = t4.z; v[j * 4 + 3] = t4.w;
                s += t4.x + t4.y + t4.z + t4.w;
                s2 += t4.x * t4.x + t4.y * t4.y + t4.z * t4.z + t4.w * t4.w;
            }
            s += __shfl_xor(s, 1);            // pair (2k,2k+1) shares one pixel
            s2 += __shfl_xor(s2, 1);
            float mu = s * (1.f / CC);
            float var = s2 * (1.f / CC) - mu * mu;
            float rs = rsqrtf(var + 1e-3f);
            f16 o16[16];
#pragma unroll
            for (int c = 0; c < 16; c++)
                o16[c] = (f16)((v[c] - mu) * rs * sg[part * 16 + c] + sb[part * 16 + c]);
            f16x8* d = (f16x8*)&xpatch[pix * 72 + part * 16];
            d[0] = *(f16x8*)&o16[0];
            d[1] = *(f16x8*)&o16[8];
        }
    }
}

// ======== Fused: 16 ConvLSTM steps, h resident in LDS, halo-only cross-block traffic ========
// 256 blocks x 512 threads = 1 block/CU (LDS 141.8 KB). Block owns one 8x8 px tile x all
// 256 gates forever (proven r4 dataflow, 213us). No fences in the hot loop (relaxed agent
// atomics for halo+flags). This round vs r4: (1) XOR slot swizzle kills the 4-quad B-read
// bank conflict; (2) x[t+1] LN staged inside phase 4 (xpatch only read in phases 0-2), so
// its HBM latency hides under phases 4-8 instead of the phase-0 barrier.
__global__ __launch_bounds__(512, 2)
void fused_kernel(const float* __restrict__ x, const float* __restrict__ gamma,
                  const float* __restrict__ beta, const f16* __restrict__ wcatF,
                  const float* __restrict__ bs, f16* __restrict__ halo,
                  float* __restrict__ out, unsigned* __restrict__ flags) {
    __shared__ __align__(16) f16 patches[3 * 7200];  // xpatch + hpatch[2], 43.2 KB
    __shared__ __align__(16) f16 wbuf[2 * 24576];    // 2 x 12 pieces x 4096 B
    __shared__ float sg[CC], sb[CC];

    f16* xpatch = patches;
    int tid = threadIdx.x;
    int tile = blockIdx.x;
    int bb = tile >> 6, ty = (tile >> 3) & 7, tx = tile & 7;
    int lane = tid & 63, w = tid >> 6;          // w in [0,8)
    int wm = w >> 2, nhalf = (w >> 1) & 1, wn = w & 1;
    int quad = lane >> 4, noff = lane & 15;

    if (tid < CC) sg[tid] = gamma[tid];
    else if (tid < 2 * CC) sb[tid - CC] = beta[tid - CC];

    // zero patch buffers once: out-of-image borders stay zero forever; h0 = 0
    for (int i = tid; i < 2700; i += 512)
        ((f16x8*)patches)[i] = (f16x8){0, 0, 0, 0, 0, 0, 0, 0};

    // per-lane global weight addresses: instr g = w*6+i covers piece j = g>>2,
    // slots (g&3)*64 + lane. Source is 64 lanes x 16B contiguous (coalesced);
    // the XOR permutation is baked into wcatF's slot order, so the copy stays linear.
    const char* gw[6];
#pragma unroll
    for (int i = 0; i < 6; i++) {
        int g = w * 6 + i;                    // [0,48)
        gw[i] = (const char*)wcatF + ((size_t)(g >> 2) * 256 + (g & 3) * 64 + lane) * 16;
    }

    int fch = (nhalf << 5) + (wn << 4) + noff;  // f-channel in [0,64)
    float b_i = bs[fch], b_f = bs[64 + fch], b_c = bs[128 + fch], b_o = bs[192 + fch];

    float creg[2][4];
#pragma unroll
    for (int mt = 0; mt < 2; mt++)
#pragma unroll
        for (int r = 0; r < 4; r++) creg[mt][r] = 0.f;

    // per-thread A-read pixel bases (constant across steps)
    int mrow[2];
#pragma unroll
    for (int mt = 0; mt < 2; mt++) {
        int m = (wm << 5) + (mt << 4) + noff;
        mrow[mt] = ((m >> 3) * 10 + (m & 7)) * 72 + (quad << 3);
    }
    // B-read slot offsets, XOR-swizzled per quad (matches wprep's slot permutation)
    int rBx[4];
#pragma unroll
    for (int cls = 0; cls < 4; cls++)
        rBx[cls] = ((((cls << 6) + fch) ^ (quad << 1)) << 3);

    __syncthreads();  // patch zeroing + sg/sb visible

    // initial weight prefetch: phase 0 -> buffer 0; stage x[0]
#pragma unroll
    for (int i = 0; i < 6; i++) {
        int g = w * 6 + i;
        async_copy16(gw[i], &wbuf[(g >> 2) * 2048 + (g & 3) * 512]);
    }
    stage_x_ln(x, bb, 0, ty, tx, tid, sg, sb, xpatch);

    for (int t = 0; t < TT; t++) {
        f16* hp_cur = patches + 7200 + (t & 1) * 7200;
        f16* hp_nxt = patches + 7200 + ((t + 1) & 1) * 7200;
        f16* wrd0 = &wbuf[(t & 1) * 24576];       // parity buffer for even phases
        f16* wrd1 = &wbuf[((t + 1) & 1) * 24576]; // parity buffer for odd phases

        f32x4 acc[2][4];
#pragma unroll
        for (int i = 0; i < 2; i++)
#pragma unroll
            for (int j = 0; j < 4; j++) acc[i][j] = (f32x4){0.f, 0.f, 0.f, 0.f};

        // ---- 9 phases, fully unrolled: all tap/parity math compile-time ----
#pragma unroll
        for (int p = 0; p < 9; ++p) {
            __syncthreads();  // drains vmcnt -> read buffer ready; prior reads of write buffer done
            {
                int nc = (p == 8) ? 0 : p + 1;    // p=8 prefetches next step's phase 0
                f16* wdst = (p & 1) ? wrd0 : wrd1;
#pragma unroll
                for (int i = 0; i < 6; i++) {
                    int g = w * 6 + i;
                    async_copy16(gw[i] + (size_t)nc * 49152,
                                 &wdst[(g >> 2) * 2048 + (g & 3) * 512]);
                }
            }
            const f16* wbp = (p & 1) ? wrd1 : wrd0;
#pragma unroll
            for (int cw = 0; cw < 3; ++cw) {
                int c = p * 3 + cw;               // compile-time
                bool isx = c < 9;
                int hc = c - 9;
                int tap = isx ? c : (hc >> 1);
                int coff = isx ? 0 : ((hc & 1) << 5);
                const f16* ap = isx ? xpatch : hp_cur;
                int dy = tap / 3, dx = tap % 3;
                int toff = (dy * 10 + dx) * 72 + coff;   // compile-time immediate
                f16x8 a[2];
#pragma unroll
                for (int mt = 0; mt < 2; mt++)
                    a[mt] = *(const f16x8*)&ap[mrow[mt] + toff];
#pragma unroll
                for (int cls = 0; cls < 4; cls++) {
                    f16x8 bf = *(const f16x8*)&wbp[((cw << 2) + quad) * 2048 + rBx[cls]];
                    acc[0][cls] = __builtin_amdgcn_mfma_f32_16x16x32_f16(a[0], bf, acc[0][cls], 0, 0, 0);
                    acc[1][cls] = __builtin_amdgcn_mfma_f32_16x16x32_f16(a[1], bf, acc[1][cls], 0, 0, 0);
                }
            }
            // ---- halo staging folded into phase 2 (h first consumed at phase 3) ----
            if (p == 2 && t > 0 && tid >= 256 && tid < 400) {
                int e = tid - 256;                // [0,144): 36 ring px x 4 quarters of 16ch
                int hx = e >> 2, quarter = e & 3;
                int py, px_;
                if (hx < 10)      { py = 0; px_ = hx; }
                else if (hx < 20) { py = 9; px_ = hx - 10; }
                else if (hx < 28) { py = 1 + (hx - 20); px_ = 0; }
                else              { py = 1 + (hx - 28); px_ = 9; }
                int gy = ty * 8 - 1 + py, gx = tx * 8 - 1 + px_;
                if (gy >= 0 && gy < HH && gx >= 0 && gx < WW) {
                    int nb = bb * 64 + ((gy >> 3) << 3) + (gx >> 3);
                    while (__hip_atomic_load(&flags[nb], __ATOMIC_RELAXED,
                                             __HIP_MEMORY_SCOPE_AGENT) < (unsigned)t)
                        __builtin_amdgcn_s_sleep(1);
                    const ull* src = (const ull*)(halo + ((size_t)(t * BB + bb) * (HH * WW)
                                                         + gy * WW + gx) * FF) + quarter * 4;
                    f16* dst = &hp_cur[(py * 10 + px_) * 72 + quarter * 16];
#pragma unroll
                    for (int j = 0; j < 4; j++) {
                        ull vv = __hip_atomic_load(src + j, __ATOMIC_RELAXED,
                                                   __HIP_MEMORY_SCOPE_AGENT);
                        *(ull*)(dst + j * 4) = vv;
                    }
                }
            }
            // ---- stage x[t+1] in phase 4 (xpatch only read in phases 0-2) ----
            if (p == 4 && t + 1 < TT)
                stage_x_ln(x, bb, t + 1, ty, tx, tid, sg, sb, xpatch);
        }

        // ---- epilogue: gates + state; h -> LDS (next patch) + ring -> global ----
#pragma unroll
        for (int mt = 0; mt < 2; mt++) {
#pragma unroll
            for (int r = 0; r < 4; r++) {
                int m = (wm << 5) + (mt << 4) + (quad << 2) + r;  // C/D row = quad*4+reg
                int py8 = m >> 3, px8 = m & 7;
                float zi = acc[mt][0][r] + b_i;
                float zf = acc[mt][1][r] + b_f;
                float zc = acc[mt][2][r] + b_c;
                float zo = acc[mt][3][r] + b_o;
                float ig = hsig(zi), fg = hsig(zf), og = hsig(zo);
                float cn = fg * creg[mt][r] + ig * tanh_fast(zc);
                creg[mt][r] = cn;
                f16 hval = (f16)(og * tanh_fast(cn));
                hp_nxt[((py8 + 1) * 10 + px8 + 1) * 72 + fch] = hval;
                if (py8 == 0 || py8 == 7 || px8 == 0 || px8 == 7) {
                    union { f16 f; unsigned short u; } cvt; cvt.f = hval;
                    unsigned short* hp = (unsigned short*)halo
                        + ((size_t)((t + 1) * BB + bb) * (HH * WW)
                           + (ty * 8 + py8) * WW + (tx * 8 + px8)) * FF + fch;
                    __hip_atomic_store(hp, cvt.u, __ATOMIC_RELAXED, __HIP_MEMORY_SCOPE_AGENT);
                }
            }
        }
        __syncthreads();  // hp_nxt complete; each wave's vmcnt(0) => ring stores coherent
        if (tid == 0)
            __hip_atomic_store(&flags[tile], (unsigned)(t + 1), __ATOMIC_RELAXED,
                               __HIP_MEMORY_SCOPE_AGENT);

        // ---- pool 2x2 from hp_nxt -> out (interior px only; no race with halo writes) ----
        {
            int o = tid * 2;
            int f0 = o & 63;
            int ox2 = (o >> 6) & 3, oy2 = (o >> 8) & 3;
            int row = 1 + oy2 * 2, col = 1 + ox2 * 2;
            const f16* hb = &hp_nxt[(row * 10 + col) * 72 + f0];
            float v0 = fmaxf(fmaxf((float)hb[0], (float)hb[72]),
                             fmaxf((float)hb[720], (float)hb[792]));
            float v1 = fmaxf(fmaxf((float)hb[1], (float)hb[73]),
                             fmaxf((float)hb[721], (float)hb[793]));
            size_t ofs = (((size_t)(bb * TT + t) * 32 + (ty * 4 + oy2)) * 32
                          + (tx * 4 + ox2)) * 64 + f0;
            float2 v2; v2.x = v0; v2.y = v1;
            *(float2*)(out + ofs) = v2;
        }
    }
}

// ================= Fallback path (round-4 proven multi-kernel, uses wcatB) =================
__global__ void ln_kernel(const float* __restrict__ x,
                          const float* __restrict__ gamma,
                          const float* __restrict__ beta,
                          f16* __restrict__ xn) {
    __shared__ float sg[CC], sb[CC];
    if (threadIdx.x < CC) sg[threadIdx.x] = gamma[threadIdx.x];
    else if (threadIdx.x < 2 * CC) sb[threadIdx.x - CC] = beta[threadIdx.x - CC];
    __syncthreads();
    int q = blockIdx.x * 256 + threadIdx.x;
    const float* xp = x + (size_t)q * CC;
    float v[CC];
    float s = 0.f, s2 = 0.f;
#pragma unroll
    for (int c = 0; c < CC; c += 4) {
        float4 t4 = *(const float4*)(xp + c);
        v[c] = t4.x; v[c + 1] = t4.y; v[c + 2] = t4.z; v[c + 3] = t4.w;
        s += t4.x + t4.y + t4.z + t4.w;
        s2 += t4.x * t4.x + t4.y * t4.y + t4.z * t4.z + t4.w * t4.w;
    }
    float mu = s * (1.f / CC);
    float var = s2 * (1.f / CC) - mu * mu;
    float rs = rsqrtf(var + 1e-3f);
    f16 o[CC];
#pragma unroll
    for (int c = 0; c < CC; c++)
        o[c] = (f16)((v[c] - mu) * rs * sg[c] + sb[c]);
    f16x8* d = (f16x8*)(xn + (size_t)q * CC);
#pragma unroll
    for (int c = 0; c < 4; c++) d[c] = *(f16x8*)&o[c * 8];
}

__global__ __launch_bounds__(256, 2)
void step_kernel(const f16* __restrict__ xn, const f16* __restrict__ wcat,
                 const float* __restrict__ bs,
                 float* __restrict__ cst, f16* __restrict__ hs, int t) {
    __shared__ __align__(16) f16 xpatch[100 * 72];
    __shared__ __align__(16) f16 hpatch[100 * 72];
    __shared__ __align__(16) f16 wbuf[2 * 12288];

    int tile = blockIdx.x >> 1, nhalf = blockIdx.x & 1;
    int bb = tile >> 6, ty = (tile >> 3) & 7, tx = tile & 7;
    int tid = threadIdx.x;
    int lane = tid & 63, w = tid >> 6;
    int wm = w >> 1, wn = w & 1;
    int quad = lane >> 4, noff = lane & 15;

    const char* gw[6];
#pragma unroll
    for (int i = 0; i < 6; i++) {
        int g = w * 6 + i;
        int hb = g & 1;
        int gate = (((hb << 1) + (lane >> 5)) << 6) + (nhalf << 5) + (lane & 31);
        gw[i] = (const char*)wcat + ((size_t)(g >> 1) * 256 + gate) * 16;
    }
#pragma unroll
    for (int i = 0; i < 6; i++) {
        int g = w * 6 + i;
        async_copy16(gw[i], &wbuf[(g >> 1) * 1024 + (g & 1) * 512]);
    }

    const f16* xslice = xn + (size_t)(bb * TT + t) * (HH * WW) * CC;
    const f16* hprev = hs + (size_t)t * (BB * HH * WW * FF);
    f16* hnew = hs + (size_t)(t + 1) * (BB * HH * WW * FF);

    if (tid < 200) {
        int pix = tid >> 1, part = tid & 1;
        int py = pix / 10, px = pix % 10;
        int y = ty * 8 - 1 + py, x = tx * 8 - 1 + px;
        bool in = (y >= 0 && y < HH && x >= 0 && x < WW);
        f16x8 z = {0, 0, 0, 0, 0, 0, 0, 0};
        {
            f16x8* d = (f16x8*)&xpatch[pix * 72 + part * 16];
            if (in) {
                const f16x8* s = (const f16x8*)(xslice + ((size_t)y * WW + x) * CC + part * 16);
                d[0] = s[0]; d[1] = s[1];
            } else { d[0] = z; d[1] = z; }
        }
        {
            f16x8* d = (f16x8*)&hpatch[pix * 72 + part * 32];
            if (in) {
                const f16x8* s = (const f16x8*)(hprev + ((size_t)(bb * HH + y) * WW + x) * FF + part * 32);
                d[0] = s[0]; d[1] = s[1]; d[2] = s[2]; d[3] = s[3];
            } else { d[0] = z; d[1] = z; d[2] = z; d[3] = z; }
        }
    }

    int fch = (nhalf << 5) + (wn << 4) + noff;
    float b_i = bs[fch], b_f = bs[64 + fch], b_c = bs[128 + fch], b_o = bs[192 + fch];

    f32x4 acc[2][4];
#pragma unroll
    for (int i = 0; i < 2; i++)
#pragma unroll
        for (int j = 0; j < 4; j++) acc[i][j] = (f32x4){0.f, 0.f, 0.f, 0.f};

#pragma unroll
    for (int p = 0; p < 9; ++p) {
        __syncthreads();
        if (p < 8) {
#pragma unroll
            for (int i = 0; i < 6; i++) {
                int g = w * 6 + i;
                async_copy16(gw[i] + (size_t)(p + 1) * 49152,
                             &wbuf[((p + 1) & 1) * 12288 + (g >> 1) * 1024 + (g & 1) * 512]);
            }
        }
        const f16* wb = &wbuf[(p & 1) * 12288];
#pragma unroll
        for (int cw = 0; cw < 3; ++cw) {
            int c = p * 3 + cw;
            bool isx = c < 9;
            int hc = c - 9;
            int tap = isx ? c : (hc >> 1);
            int coff = isx ? 0 : ((hc & 1) << 5);
            const f16* ap = isx ? xpatch : hpatch;
            int dy = tap / 3, dx = tap % 3;
            f16x8 a[2];
#pragma unroll
            for (int mt = 0; mt < 2; mt++) {
                int m = (wm << 5) + (mt << 4) + noff;
                int pp = ((m >> 3) + dy) * 10 + (m & 7) + dx;
                a[mt] = *(const f16x8*)&ap[pp * 72 + coff + (quad << 3)];
            }
#pragma unroll
            for (int cls = 0; cls < 4; cls++) {
                f16x8 bf = *(const f16x8*)&wb[((cw << 2) + quad) * 1024 + (((cls << 5) + (wn << 4) + noff) << 3)];
                acc[0][cls] = __builtin_amdgcn_mfma_f32_16x16x32_f16(a[0], bf, acc[0][cls], 0, 0, 0);
                acc[1][cls] = __builtin_amdgcn_mfma_f32_16x16x32_f16(a[1], bf, acc[1][cls], 0, 0, 0);
            }
        }
    }

#pragma unroll
    for (int mt = 0; mt < 2; mt++) {
#pragma unroll
        for (int r = 0; r < 4; r++) {
            int m = (wm << 5) + (mt << 4) + (quad << 2) + r;
            int y = ty * 8 + (m >> 3), x = tx * 8 + (m & 7);
            size_t p = (size_t)(bb * HH + y) * WW + x;
            float zi = acc[mt][0][r] + b_i;
            float zf = acc[mt][1][r] + b_f;
            float zc = acc[mt][2][r] + b_c;
            float zo = acc[mt][3][r] + b_o;
            float ig = hsig(zi), fg = hsig(zf), og = hsig(zo);
            float cold = cst[p * FF + fch];
            float cn = fg * cold + ig * tanh_fast(zc);
            cst[p * FF + fch] = cn;
            hnew[p * FF + fch] = (f16)(og * tanh_fast(cn));
        }
    }
}

__global__ void pool_kernel(const f16* __restrict__ hs, float* __restrict__ out) {
    int idx = blockIdx.x * 256 + threadIdx.x;
    int f = idx & 63;
    int ox = (idx >> 6) & 31;
    int oy = (idx >> 11) & 31;
    int t = (idx >> 16) & 15;
    int bb = idx >> 20;
    const f16* base = hs + (size_t)(t + 1) * (BB * HH * WW * FF)
                    + ((size_t)(bb * HH + oy * 2) * WW + ox * 2) * FF + f;
    float v0 = (float)base[0];
    float v1 = (float)base[FF];
    float v2 = (float)base[WW * FF];
    float v3 = (float)base[WW * FF + FF];
    out[idx] = fmaxf(fmaxf(v0, v1), fmaxf(v2, v3));
}

extern "C" void kernel_launch(void* const* d_in, const int* in_sizes, int n_in,
                              void* d_out, int out_size, void* d_ws, size_t ws_size,
                              hipStream_t stream) {
    const float* x = (const float*)d_in[0];
    const float* gamma = (const float*)d_in[1];
    const float* beta = (const float*)d_in[2];
    const float* wx = (const float*)d_in[3];
    const float* wh = (const float*)d_in[4];
    const float* bs = (const float*)d_in[5];
    float* out = (float*)d_out;

    // workspace layout (all 16B-aligned)
    char* ws = (char*)d_ws;
    f16* xn = (f16*)ws;                       // 16,777,216 B (fallback only)
    f16* wcatB = (f16*)(ws + 16777216);       //    442,368 B (fallback layout)
    float* cst = (float*)(ws + 17219584);     //  4,194,304 B (fallback c-state; fused: flags)
    f16* hs = (f16*)(ws + 21413888);          // 35,651,584 B (h history / halo)
    f16* wcatF = (f16*)(ws + 57065472);       //    442,368 B (fused XOR-swizzled layout)
    unsigned* flags = (unsigned*)cst;         // 256 x 4 B, disjoint usage

    hipMemsetAsync(flags, 0, 256 * 4, stream);
    wprep_kernel<<<864, 256, 0, stream>>>(wx, wh, wcatF, wcatB);

    void* args[8];
    args[0] = (void*)&x;
    args[1] = (void*)&gamma;
    args[2] = (void*)&beta;
    args[3] = (void*)&wcatF;
    args[4] = (void*)&bs;
    args[5] = (void*)&hs;     // halo buffer
    args[6] = (void*)&out;
    args[7] = (void*)&flags;
    hipError_t err = hipLaunchCooperativeKernel((const void*)fused_kernel, dim3(256),
                                                dim3(512), args, 0, stream);
    if (err != hipSuccess) {
        (void)hipGetLastError();  // clear error state; take the proven multi-kernel path
        hipMemsetAsync(cst, 0, (size_t)BB * HH * WW * FF * 4, stream);
        hipMemsetAsync(hs, 0, (size_t)BB * HH * WW * FF * 2, stream);
        ln_kernel<<<1024, 256, 0, stream>>>(x, gamma, beta, xn);
        for (int t = 0; t < TT; t++)
            step_kernel<<<512, 256, 0, stream>>>(xn, wcatB, bs, cst, hs, t);
        pool_kernel<<<16384, 256, 0, stream>>>(hs, out);
    }
}

// Round 8
// 265.154 us; speedup vs baseline: 1.3272x; 1.3272x over previous
//
#include <hip/hip_runtime.h>
#include <hip/hip_fp16.h>

typedef _Float16 f16;
typedef _Float16 f16x8 __attribute__((ext_vector_type(8)));
typedef float f32x4 __attribute__((ext_vector_type(4)));
typedef unsigned long long ull;

#define BB 4
#define TT 16
#define HH 64
#define WW 64
#define CC 32
#define FF 64
#define GG 256  // 4F gates

__device__ __forceinline__ float hsig(float z) {
    return fminf(fmaxf(0.2f * z + 0.5f, 0.f), 1.f);
}
__device__ __forceinline__ float tanh_fast(float x) {
    return 1.f - 2.f / (__expf(2.f * x) + 1.f);
}

__device__ __forceinline__ void async_copy16(const void* g, void* l) {
    __builtin_amdgcn_global_load_lds(
        (const __attribute__((address_space(1))) unsigned*)g,
        (__attribute__((address_space(3))) unsigned*)l, 16, 0, 0);
}

// --- Weight prep, piece-major (r4 proven): wcat[phase p][piece j][gate n][elem e] ---
// k = p*96 + j*8 + e  (k in [0,864): 0..288 = Wx taps (tap*32+c), 288..864 = Wh (288+tap*64+f))
// Makes global_load_lds sources contiguous (64 lanes x 16B) and B-fragment ds_reads clean.
__global__ void wprep_kernel(const float* __restrict__ wx, const float* __restrict__ wh,
                             f16* __restrict__ wcat) {
    int e = blockIdx.x * 256 + threadIdx.x;
    if (e < 9 * CC * GG) {                    // 73728: Wx, e = (tap*32+c)*256 + n
        int n = e & 255, k = e >> 8;
        int p = k / 96, r = k % 96;
        wcat[((p * 12 + (r >> 3)) * 256 + n) * 8 + (r & 7)] = (f16)wx[e];
    } else {
        e -= 9 * CC * GG;
        if (e < 9 * FF * GG) {                // 147456: Wh, e = (tap*64+f)*256 + n
            int n = e & 255, k = 288 + (e >> 8);
            int p = k / 96, r = k % 96;
            wcat[((p * 12 + (r >> 3)) * 256 + n) * 8 + (r & 7)] = (f16)wh[e];
        }
    }
}

// ======== Fused: 16 ConvLSTM steps, h resident in LDS, halo-only cross-block traffic ========
// 256 blocks x 512 threads = 1 block/CU BY CAPACITY (141.8 KB LDS, 512 thr): every block is
// resident from dispatch, so the relaxed-atomic flags protocol needs no cooperative launch
// (which cost ~70us/replay of launch overhead). Kernel body is byte-identical to the proven
// r4 version (213us dispatch): piece-major wbuf, fully unrolled 9-phase loop, halo staged in
// phase 2 (consumed from phase 3), LN fused into x staging, pool fused into the epilogue.
__global__ __launch_bounds__(512, 2)
void fused_kernel(const float* __restrict__ x, const float* __restrict__ gamma,
                  const float* __restrict__ beta, const f16* __restrict__ wcat,
                  const float* __restrict__ bs, f16* __restrict__ halo,
                  float* __restrict__ out, unsigned* __restrict__ flags) {
    __shared__ __align__(16) f16 patches[3 * 7200];  // xpatch + hpatch[2], 43.2 KB
    __shared__ __align__(16) f16 wbuf[2 * 24576];    // 2 x 48 KB: 12 pieces x 256 rows x 16B
    __shared__ float sg[CC], sb[CC];

    f16* xpatch = patches;
    int tid = threadIdx.x;
    int tile = blockIdx.x;
    int bb = tile >> 6, ty = (tile >> 3) & 7, tx = tile & 7;
    int lane = tid & 63, w = tid >> 6;          // w in [0,8)
    int wm = w >> 2, nhalf = (w >> 1) & 1, wn = w & 1;
    int quad = lane >> 4, noff = lane & 15;

    if (tid < CC) sg[tid] = gamma[tid];
    else if (tid < 2 * CC) sb[tid - CC] = beta[tid - CC];

    // zero patch buffers once: out-of-image borders stay zero forever; h0 = 0
    for (int i = tid; i < 2700; i += 512)
        ((f16x8*)patches)[i] = (f16x8){0, 0, 0, 0, 0, 0, 0, 0};

    // per-lane global weight addresses: instr g = w*6+i covers piece j = g>>2,
    // gate rows (g&3)*64 + lane. Source is 64 lanes x 16B contiguous (coalesced).
    const char* gw[6];
#pragma unroll
    for (int i = 0; i < 6; i++) {
        int g = w * 6 + i;                    // [0,48)
        gw[i] = (const char*)wcat + ((size_t)(g >> 2) * 256 + (g & 3) * 64 + lane) * 16;
    }

    int fch = (nhalf << 5) + (wn << 4) + noff;  // f-channel in [0,64)
    float b_i = bs[fch], b_f = bs[64 + fch], b_c = bs[128 + fch], b_o = bs[192 + fch];

    float creg[2][4];
#pragma unroll
    for (int mt = 0; mt < 2; mt++)
#pragma unroll
        for (int r = 0; r < 4; r++) creg[mt][r] = 0.f;

    // per-thread A-read pixel bases (constant across steps)
    int mrow[2];
#pragma unroll
    for (int mt = 0; mt < 2; mt++) {
        int m = (wm << 5) + (mt << 4) + noff;
        mrow[mt] = ((m >> 3) * 10 + (m & 7)) * 72 + (quad << 3);
    }
    // B-read gate-row offsets (f16 units within a piece region)
    int rB[4];
#pragma unroll
    for (int cls = 0; cls < 4; cls++) rB[cls] = ((cls << 6) + fch) << 3;

    __syncthreads();  // patch zeroing + sg/sb visible

    // initial weight prefetch: phase 0 -> buffer 0
#pragma unroll
    for (int i = 0; i < 6; i++) {
        int g = w * 6 + i;
        async_copy16(gw[i], &wbuf[(g >> 2) * 2048 + (g & 3) * 512]);
    }

    for (int t = 0; t < TT; t++) {
        f16* hp_cur = patches + 7200 + (t & 1) * 7200;
        f16* hp_nxt = patches + 7200 + ((t + 1) & 1) * 7200;
        f16* wrd0 = &wbuf[(t & 1) * 24576];       // parity buffer for even phases
        f16* wrd1 = &wbuf[((t + 1) & 1) * 24576]; // parity buffer for odd phases

        // ---- staging: x-LN -> xpatch (tid<200); halo staged later, inside phase 2 ----
        if (tid < 200) {
            int pix = tid >> 1, part = tid & 1;
            int py = pix / 10, px_ = pix % 10;
            int gy = ty * 8 - 1 + py, gx = tx * 8 - 1 + px_;
            if (gy >= 0 && gy < HH && gx >= 0 && gx < WW) {
                const float* xp = x + ((size_t)(bb * TT + t) * (HH * WW)
                                       + gy * WW + gx) * CC + part * 16;
                float v[16];
                float s = 0.f, s2 = 0.f;
#pragma unroll
                for (int j = 0; j < 4; j++) {
                    float4 t4 = *(const float4*)(xp + j * 4);
                    v[j * 4] = t4.x; v[j * 4 + 1] = t4.y; v[j * 4 + 2] = t4.z; v[j * 4 + 3] = t4.w;
                    s += t4.x + t4.y + t4.z + t4.w;
                    s2 += t4.x * t4.x + t4.y * t4.y + t4.z * t4.z + t4.w * t4.w;
                }
                s += __shfl_xor(s, 1);            // pair (2k,2k+1) shares one pixel
                s2 += __shfl_xor(s2, 1);
                float mu = s * (1.f / CC);
                float var = s2 * (1.f / CC) - mu * mu;
                float rs = rsqrtf(var + 1e-3f);
                f16 o16[16];
#pragma unroll
                for (int c = 0; c < 16; c++)
                    o16[c] = (f16)((v[c] - mu) * rs * sg[part * 16 + c] + sb[part * 16 + c]);
                f16x8* d = (f16x8*)&xpatch[pix * 72 + part * 16];
                d[0] = *(f16x8*)&o16[0];
                d[1] = *(f16x8*)&o16[8];
            }
        }

        f32x4 acc[2][4];
#pragma unroll
        for (int i = 0; i < 2; i++)
#pragma unroll
            for (int j = 0; j < 4; j++) acc[i][j] = (f32x4){0.f, 0.f, 0.f, 0.f};

        // ---- 9 phases, fully unrolled: all tap/parity math compile-time ----
#pragma unroll
        for (int p = 0; p < 9; ++p) {
            __syncthreads();  // drains vmcnt -> read buffer ready; prior reads of write buffer done
            {
                int nc = (p == 8) ? 0 : p + 1;    // p=8 prefetches next step's phase 0
                f16* wdst = (p & 1) ? wrd0 : wrd1;
#pragma unroll
                for (int i = 0; i < 6; i++) {
                    int g = w * 6 + i;
                    async_copy16(gw[i] + (size_t)nc * 49152,
                                 &wdst[(g >> 2) * 2048 + (g & 3) * 512]);
                }
            }
            const f16* wbp = (p & 1) ? wrd1 : wrd0;
#pragma unroll
            for (int cw = 0; cw < 3; ++cw) {
                int c = p * 3 + cw;               // compile-time
                bool isx = c < 9;
                int hc = c - 9;
                int tap = isx ? c : (hc >> 1);
                int coff = isx ? 0 : ((hc & 1) << 5);
                const f16* ap = isx ? xpatch : hp_cur;
                int dy = tap / 3, dx = tap % 3;
                int toff = (dy * 10 + dx) * 72 + coff;   // compile-time immediate
                f16x8 a[2];
#pragma unroll
                for (int mt = 0; mt < 2; mt++)
                    a[mt] = *(const f16x8*)&ap[mrow[mt] + toff];
#pragma unroll
                for (int cls = 0; cls < 4; cls++) {
                    f16x8 bf = *(const f16x8*)&wbp[((cw << 2) + quad) * 2048 + rB[cls]];
                    acc[0][cls] = __builtin_amdgcn_mfma_f32_16x16x32_f16(a[0], bf, acc[0][cls], 0, 0, 0);
                    acc[1][cls] = __builtin_amdgcn_mfma_f32_16x16x32_f16(a[1], bf, acc[1][cls], 0, 0, 0);
                }
            }
            // ---- halo staging folded into phase 2 (h first consumed at phase 3) ----
            if (p == 2 && t > 0 && tid >= 256 && tid < 400) {
                int e = tid - 256;                // [0,144): 36 ring px x 4 quarters of 16ch
                int hx = e >> 2, quarter = e & 3;
                int py, px_;
                if (hx < 10)      { py = 0; px_ = hx; }
                else if (hx < 20) { py = 9; px_ = hx - 10; }
                else if (hx < 28) { py = 1 + (hx - 20); px_ = 0; }
                else              { py = 1 + (hx - 28); px_ = 9; }
                int gy = ty * 8 - 1 + py, gx = tx * 8 - 1 + px_;
                if (gy >= 0 && gy < HH && gx >= 0 && gx < WW) {
                    int nb = bb * 64 + ((gy >> 3) << 3) + (gx >> 3);
                    while (__hip_atomic_load(&flags[nb], __ATOMIC_RELAXED,
                                             __HIP_MEMORY_SCOPE_AGENT) < (unsigned)t)
                        __builtin_amdgcn_s_sleep(1);
                    const ull* src = (const ull*)(halo + ((size_t)(t * BB + bb) * (HH * WW)
                                                         + gy * WW + gx) * FF) + quarter * 4;
                    f16* dst = &hp_cur[(py * 10 + px_) * 72 + quarter * 16];
#pragma unroll
                    for (int j = 0; j < 4; j++) {
                        ull vv = __hip_atomic_load(src + j, __ATOMIC_RELAXED,
                                                   __HIP_MEMORY_SCOPE_AGENT);
                        *(ull*)(dst + j * 4) = vv;
                    }
                }
            }
        }

        // ---- epilogue: gates + state; h -> LDS (next patch) + ring -> global ----
#pragma unroll
        for (int mt = 0; mt < 2; mt++) {
#pragma unroll
            for (int r = 0; r < 4; r++) {
                int m = (wm << 5) + (mt << 4) + (quad << 2) + r;  // C/D row = quad*4+reg
                int py8 = m >> 3, px8 = m & 7;
                float zi = acc[mt][0][r] + b_i;
                float zf = acc[mt][1][r] + b_f;
                float zc = acc[mt][2][r] + b_c;
                float zo = acc[mt][3][r] + b_o;
                float ig = hsig(zi), fg = hsig(zf), og = hsig(zo);
                float cn = fg * creg[mt][r] + ig * tanh_fast(zc);
                creg[mt][r] = cn;
                f16 hval = (f16)(og * tanh_fast(cn));
                hp_nxt[((py8 + 1) * 10 + px8 + 1) * 72 + fch] = hval;
                if (py8 == 0 || py8 == 7 || px8 == 0 || px8 == 7) {
                    union { f16 f; unsigned short u; } cvt; cvt.f = hval;
                    unsigned short* hp = (unsigned short*)halo
                        + ((size_t)((t + 1) * BB + bb) * (HH * WW)
                           + (ty * 8 + py8) * WW + (tx * 8 + px8)) * FF + fch;
                    __hip_atomic_store(hp, cvt.u, __ATOMIC_RELAXED, __HIP_MEMORY_SCOPE_AGENT);
                }
            }
        }
        __syncthreads();  // hp_nxt complete; each wave's vmcnt(0) => ring stores coherent
        if (tid == 0)
            __hip_atomic_store(&flags[tile], (unsigned)(t + 1), __ATOMIC_RELAXED,
                               __HIP_MEMORY_SCOPE_AGENT);

        // ---- pool 2x2 from hp_nxt -> out (interior px only; no race with halo writes) ----
        {
            int o = tid * 2;
            int f0 = o & 63;
            int ox2 = (o >> 6) & 3, oy2 = (o >> 8) & 3;
            int row = 1 + oy2 * 2, col = 1 + ox2 * 2;
            const f16* hb = &hp_nxt[(row * 10 + col) * 72 + f0];
            float v0 = fmaxf(fmaxf((float)hb[0], (float)hb[72]),
                             fmaxf((float)hb[720], (float)hb[792]));
            float v1 = fmaxf(fmaxf((float)hb[1], (float)hb[73]),
                             fmaxf((float)hb[721], (float)hb[793]));
            size_t ofs = (((size_t)(bb * TT + t) * 32 + (ty * 4 + oy2)) * 32
                          + (tx * 4 + ox2)) * 64 + f0;
            float2 v2; v2.x = v0; v2.y = v1;
            *(float2*)(out + ofs) = v2;
        }
    }
}

extern "C" void kernel_launch(void* const* d_in, const int* in_sizes, int n_in,
                              void* d_out, int out_size, void* d_ws, size_t ws_size,
                              hipStream_t stream) {
    const float* x = (const float*)d_in[0];
    const float* gamma = (const float*)d_in[1];
    const float* beta = (const float*)d_in[2];
    const float* wx = (const float*)d_in[3];
    const float* wh = (const float*)d_in[4];
    const float* bs = (const float*)d_in[5];
    float* out = (float*)d_out;

    // workspace layout (all 16B-aligned)
    char* ws = (char*)d_ws;
    f16* wcat = (f16*)(ws + 16777216);        //    442,368 B (piece-major layout)
    unsigned* flags = (unsigned*)(ws + 17219584);  // 256 x 4 B
    f16* hs = (f16*)(ws + 21413888);          // 35,651,584 B (halo exchange buffer)

    hipMemsetAsync(flags, 0, 256 * 4, stream);
    wprep_kernel<<<864, 256, 0, stream>>>(wx, wh, wcat);

    // Regular launch: 256 blocks x 512 threads x 141.8 KB LDS = exactly 1 block/CU by
    // capacity -> all blocks resident at dispatch; the flags protocol needs nothing more.
    // (Cooperative launch measured ~70us/replay of extra overhead; grid.sync is not used.)
    fused_kernel<<<256, 512, 0, stream>>>(x, gamma, beta, wcat, bs, hs, out, flags);
}

// Round 9
// 243.126 us; speedup vs baseline: 1.4474x; 1.0906x over previous
//
#include <hip/hip_runtime.h>
#include <hip/hip_fp16.h>

typedef _Float16 f16;
typedef _Float16 f16x8 __attribute__((ext_vector_type(8)));
typedef float f32x4 __attribute__((ext_vector_type(4)));
typedef unsigned long long ull;

#define BB 4
#define TT 16
#define HH 64
#define WW 64
#define CC 32
#define FF 64
#define GG 256  // 4F gates

// counted-vmcnt wait that the compiler cannot reorder memory ops across
#define WAITV(n) do { asm volatile("s_waitcnt vmcnt(" #n ")" ::: "memory"); \
                      __builtin_amdgcn_sched_barrier(0); } while (0)
// group barrier WITHOUT vmcnt drain: per-wave LDS-op drain + raw s_barrier
#define LGKBAR do { asm volatile("s_waitcnt lgkmcnt(0)" ::: "memory"); \
                    __builtin_amdgcn_s_barrier(); \
                    __builtin_amdgcn_sched_barrier(0); } while (0)

__device__ __forceinline__ float hsig(float z) {
    return fminf(fmaxf(0.2f * z + 0.5f, 0.f), 1.f);
}
__device__ __forceinline__ float tanh_fast(float x) {
    return 1.f - 2.f / (__expf(2.f * x) + 1.f);
}

__device__ __forceinline__ void async_copy16(const void* g, void* l) {
    __builtin_amdgcn_global_load_lds(
        (const __attribute__((address_space(1))) unsigned*)g,
        (__attribute__((address_space(3))) unsigned*)l, 16, 0, 0);
}

// --- Weight prep, piece-major (r4/r8 proven): wcat[phase p][piece j][gate n][elem e] ---
// k = p*96 + j*8 + e  (k in [0,864): 0..288 = Wx taps (tap*32+c), 288..864 = Wh (288+tap*64+f))
// K-chunk c = p*3+cw starts at byte c*16384 (16 KB per chunk, linear) — the fused kernel
// streams chunks with one global_load_lds pair per wave.
__global__ void wprep_kernel(const float* __restrict__ wx, const float* __restrict__ wh,
                             f16* __restrict__ wcat) {
    int e = blockIdx.x * 256 + threadIdx.x;
    if (e < 9 * CC * GG) {                    // 73728: Wx, e = (tap*32+c)*256 + n
        int n = e & 255, k = e >> 8;
        int p = k / 96, r = k % 96;
        wcat[((p * 12 + (r >> 3)) * 256 + n) * 8 + (r & 7)] = (f16)wx[e];
    } else {
        e -= 9 * CC * GG;
        if (e < 9 * FF * GG) {                // 147456: Wh, e = (tap*64+f)*256 + n
            int n = e & 255, k = 288 + (e >> 8);
            int p = k / 96, r = k % 96;
            wcat[((p * 12 + (r >> 3)) * 256 + n) * 8 + (r & 7)] = (f16)wh[e];
        }
    }
}

// x staging with fused LayerNorm (r8 proven): 200 threads, 2/pixel, pair-shfl combine
__device__ __forceinline__ void stage_x(const float* __restrict__ x, int bb, int t,
                                        int ty, int tx, int tid,
                                        const float* sg, const float* sb,
                                        f16* __restrict__ xpatch) {
    if (tid < 200) {
        int pix = tid >> 1, part = tid & 1;
        int py = pix / 10, px_ = pix % 10;
        int gy = ty * 8 - 1 + py, gx = tx * 8 - 1 + px_;
        if (gy >= 0 && gy < HH && gx >= 0 && gx < WW) {
            const float* xp = x + ((size_t)(bb * TT + t) * (HH * WW)
                                   + gy * WW + gx) * CC + part * 16;
            float v[16];
            float s = 0.f, s2 = 0.f;
#pragma unroll
            for (int j = 0; j < 4; j++) {
                float4 t4 = *(const float4*)(xp + j * 4);
                v[j * 4] = t4.x; v[j * 4 + 1] = t4.y; v[j * 4 + 2] = t4.z; v[j * 4 + 3] = t4.w;
                s += t4.x + t4.y + t4.z + t4.w;
                s2 += t4.x * t4.x + t4.y * t4.y + t4.z * t4.z + t4.w * t4.w;
            }
            s += __shfl_xor(s, 1);            // pair (2k,2k+1) shares one pixel
            s2 += __shfl_xor(s2, 1);
            float mu = s * (1.f / CC);
            float var = s2 * (1.f / CC) - mu * mu;
            float rs = rsqrtf(var + 1e-3f);
            f16 o16[16];
#pragma unroll
            for (int c = 0; c < 16; c++)
                o16[c] = (f16)((v[c] - mu) * rs * sg[part * 16 + c] + sb[part * 16 + c]);
            f16x8* d = (f16x8*)&xpatch[pix * 72 + part * 16];
            d[0] = *(f16x8*)&o16[0];
            d[1] = *(f16x8*)&o16[8];
        }
    }
}

// ======== Fused: 16 ConvLSTM steps, h in LDS, counted-vmcnt weight pipeline ========
// 256 blocks x 512 threads = 1 block/CU by capacity (139.6 KB LDS). r8 dataflow (proven
// 213us) with ONE change: the 9 draining __syncthreads per step are replaced by raw
// s_barrier + counted vmcnt (T3+T4). Weights stream through 6 x 16KB chunk-buffers
// (chunk c -> buffer c%6), prefetched one 3-chunk group ahead; vmcnt(10/8/6) before each
// chunk consume (4/2/0 in the last group) keeps 6 loads in flight ACROSS barriers, so
// L2 latency and transfer overlap compute instead of serializing at every phase.
__global__ __launch_bounds__(512, 2)
void fused_kernel(const float* __restrict__ x, const float* __restrict__ gamma,
                  const float* __restrict__ beta, const f16* __restrict__ wcat,
                  const float* __restrict__ bs, f16* __restrict__ halo,
                  float* __restrict__ out, unsigned* __restrict__ flags) {
    __shared__ __align__(16) f16 patches[3 * 7200];  // xpatch + hpatch[2], 43.2 KB
    __shared__ __align__(16) f16 wbuf[6 * 8192];     // 6 chunk-buffers x 16 KB = 96 KB
    __shared__ float sg[CC], sb[CC];

    f16* xpatch = patches;
    int tid = threadIdx.x;
    int tile = blockIdx.x;
    int bb = tile >> 6, ty = (tile >> 3) & 7, tx = tile & 7;
    int lane = tid & 63, w = tid >> 6;          // w in [0,8)
    int wm = w >> 2, nhalf = (w >> 1) & 1, wn = w & 1;
    int quad = lane >> 4, noff = lane & 15;

    if (tid < CC) sg[tid] = gamma[tid];
    else if (tid < 2 * CC) sb[tid - CC] = beta[tid - CC];

    // zero patch buffers once: out-of-image borders stay zero forever; h0 = 0
    for (int i = tid; i < 2700; i += 512)
        ((f16x8*)patches)[i] = (f16x8){0, 0, 0, 0, 0, 0, 0, 0};

    // per-lane weight base: wave w takes loads 2w, 2w+1 of each 16 KB chunk
    // (chunk c source = wcat + c*16384; dest = wbuf[(c%6)*8192 + w*1024 (+512)])
    const char* gwb = (const char*)wcat + w * 2048 + lane * 16;

    int fch = (nhalf << 5) + (wn << 4) + noff;  // f-channel in [0,64)
    float b_i = bs[fch], b_f = bs[64 + fch], b_c = bs[128 + fch], b_o = bs[192 + fch];

    float creg[2][4];
#pragma unroll
    for (int mt = 0; mt < 2; mt++)
#pragma unroll
        for (int r = 0; r < 4; r++) creg[mt][r] = 0.f;

    // per-thread A-read pixel bases (constant across steps)
    int mrow[2];
#pragma unroll
    for (int mt = 0; mt < 2; mt++) {
        int m = (wm << 5) + (mt << 4) + noff;
        mrow[mt] = ((m >> 3) * 10 + (m & 7)) * 72 + (quad << 3);
    }
    // B-read gate-row offsets (f16 units within a chunk's quad-piece)
    int rB[4];
#pragma unroll
    for (int cls = 0; cls < 4; cls++) rB[cls] = ((cls << 6) + fch) << 3;

    __syncthreads();  // patch zeroing + sg/sb visible

    // initial staging: x[0] + weight chunks 0-2 (group 0)
    stage_x(x, bb, 0, ty, tx, tid, sg, sb, xpatch);
#pragma unroll
    for (int k = 0; k < 3; k++) {
        async_copy16(gwb + (size_t)k * 16384, &wbuf[k * 8192 + w * 1024]);
        async_copy16(gwb + (size_t)k * 16384 + 1024, &wbuf[k * 8192 + w * 1024 + 512]);
    }

    for (int t = 0; t < TT; t++) {
        f16* hp_cur = patches + 7200 + (t & 1) * 7200;
        f16* hp_nxt = patches + 7200 + ((t + 1) & 1) * 7200;

        LGKBAR;  // xpatch ds_writes visible; weight loads stay in flight (no vmcnt drain)

        f32x4 acc[2][4];
#pragma unroll
        for (int i = 0; i < 2; i++)
#pragma unroll
            for (int j = 0; j < 4; j++) acc[i][j] = (f32x4){0.f, 0.f, 0.f, 0.f};

        // ---- 9 groups of 3 K-chunks; barriers never drain vmcnt ----
#pragma unroll
        for (int g = 0; g < 9; ++g) {
            if (g > 0) LGKBAR;  // group g's buffers safe to consume; g+1 overwrites g-1's
            // halo staged at group-2 START (before group-3 issue): h first read at chunk 9;
            // halo loads are newest VMEM -> consumed via compiler wait, weights unaffected
            if (g == 2 && t > 0 && tid >= 256 && tid < 400) {
                int e = tid - 256;                // [0,144): 36 ring px x 4 quarters of 16ch
                int hx = e >> 2, quarter = e & 3;
                int py, px_;
                if (hx < 10)      { py = 0; px_ = hx; }
                else if (hx < 20) { py = 9; px_ = hx - 10; }
                else if (hx < 28) { py = 1 + (hx - 20); px_ = 0; }
                else              { py = 1 + (hx - 28); px_ = 9; }
                int gy = ty * 8 - 1 + py, gx = tx * 8 - 1 + px_;
                if (gy >= 0 && gy < HH && gx >= 0 && gx < WW) {
                    int nb = bb * 64 + ((gy >> 3) << 3) + (gx >> 3);
                    while (__hip_atomic_load(&flags[nb], __ATOMIC_RELAXED,
                                             __HIP_MEMORY_SCOPE_AGENT) < (unsigned)t)
                        __builtin_amdgcn_s_sleep(1);
                    const ull* src = (const ull*)(halo + ((size_t)(t * BB + bb) * (HH * WW)
                                                         + gy * WW + gx) * FF) + quarter * 4;
                    f16* dst = &hp_cur[(py * 10 + px_) * 72 + quarter * 16];
#pragma unroll
                    for (int j = 0; j < 4; j++) {
                        ull vv = __hip_atomic_load(src + j, __ATOMIC_RELAXED,
                                                   __HIP_MEMORY_SCOPE_AGENT);
                        *(ull*)(dst + j * 4) = vv;
                    }
                }
            }
            if (g < 8) {  // prefetch group g+1 (chunks 3g+3..3g+5) one group ahead
#pragma unroll
                for (int k = 0; k < 3; k++) {
                    int c = 3 * g + 3 + k;
                    async_copy16(gwb + (size_t)c * 16384,
                                 &wbuf[(c % 6) * 8192 + w * 1024]);
                    async_copy16(gwb + (size_t)c * 16384 + 1024,
                                 &wbuf[(c % 6) * 8192 + w * 1024 + 512]);
                }
            }
#pragma unroll
            for (int cw = 0; cw < 3; ++cw) {
                int c = g * 3 + cw;               // compile-time chunk id
                // counted wait: chunk c's 2 loads are the oldest of (6 current-group +
                // 6 prefetched) outstanding -> vmcnt(10/8/6); last group has no prefetch
                if (g < 8) { if (cw == 0) WAITV(10); else if (cw == 1) WAITV(8); else WAITV(6); }
                else       { if (cw == 0) WAITV(4);  else if (cw == 1) WAITV(2); else WAITV(0); }
                bool isx = c < 9;
                int hc = c - 9;
                int tap = isx ? c : (hc >> 1);
                int coff = isx ? 0 : ((hc & 1) << 5);
                const f16* ap = isx ? xpatch : hp_cur;
                int dy = tap / 3, dx = tap % 3;
                int toff = (dy * 10 + dx) * 72 + coff;   // compile-time immediate
                f16x8 a[2];
#pragma unroll
                for (int mt = 0; mt < 2; mt++)
                    a[mt] = *(const f16x8*)&ap[mrow[mt] + toff];
                const f16* wbc = &wbuf[(c % 6) * 8192 + quad * 2048];
#pragma unroll
                for (int cls = 0; cls < 4; cls++) {
                    f16x8 bf = *(const f16x8*)&wbc[rB[cls]];
                    acc[0][cls] = __builtin_amdgcn_mfma_f32_16x16x32_f16(a[0], bf, acc[0][cls], 0, 0, 0);
                    acc[1][cls] = __builtin_amdgcn_mfma_f32_16x16x32_f16(a[1], bf, acc[1][cls], 0, 0, 0);
                }
            }
        }

        // ---- epilogue: gates + state; h -> LDS (next patch) + ring -> global ----
#pragma unroll
        for (int mt = 0; mt < 2; mt++) {
#pragma unroll
            for (int r = 0; r < 4; r++) {
                int m = (wm << 5) + (mt << 4) + (quad << 2) + r;  // C/D row = quad*4+reg
                int py8 = m >> 3, px8 = m & 7;
                float zi = acc[mt][0][r] + b_i;
                float zf = acc[mt][1][r] + b_f;
                float zc = acc[mt][2][r] + b_c;
                float zo = acc[mt][3][r] + b_o;
                float ig = hsig(zi), fg = hsig(zf), og = hsig(zo);
                float cn = fg * creg[mt][r] + ig * tanh_fast(zc);
                creg[mt][r] = cn;
                f16 hval = (f16)(og * tanh_fast(cn));
                hp_nxt[((py8 + 1) * 10 + px8 + 1) * 72 + fch] = hval;
                if (py8 == 0 || py8 == 7 || px8 == 0 || px8 == 7) {
                    union { f16 f; unsigned short u; } cvt; cvt.f = hval;
                    unsigned short* hp = (unsigned short*)halo
                        + ((size_t)((t + 1) * BB + bb) * (HH * WW)
                           + (ty * 8 + py8) * WW + (tx * 8 + px8)) * FF + fch;
                    __hip_atomic_store(hp, cvt.u, __ATOMIC_RELAXED, __HIP_MEMORY_SCOPE_AGENT);
                }
            }
        }
        __syncthreads();  // full drain: hp_nxt visible + ring stores at coherent point
        if (tid == 0)
            __hip_atomic_store(&flags[tile], (unsigned)(t + 1), __ATOMIC_RELAXED,
                               __HIP_MEMORY_SCOPE_AGENT);

        // ---- pool 2x2 from hp_nxt -> out (interior px only; disjoint from halo ring) ----
        {
            int o = tid * 2;
            int f0 = o & 63;
            int ox2 = (o >> 6) & 3, oy2 = (o >> 8) & 3;
            int row = 1 + oy2 * 2, col = 1 + ox2 * 2;
            const f16* hb = &hp_nxt[(row * 10 + col) * 72 + f0];
            float v0 = fmaxf(fmaxf((float)hb[0], (float)hb[72]),
                             fmaxf((float)hb[720], (float)hb[792]));
            float v1 = fmaxf(fmaxf((float)hb[1], (float)hb[73]),
                             fmaxf((float)hb[721], (float)hb[793]));
            size_t ofs = (((size_t)(bb * TT + t) * 32 + (ty * 4 + oy2)) * 32
                          + (tx * 4 + ox2)) * 64 + f0;
            float2 v2; v2.x = v0; v2.y = v1;
            *(float2*)(out + ofs) = v2;
        }

        // ---- next-step staging: x[t+1] + weight chunks 0-2 (buffers 0-2 free: their
        // last readers were chunks 24-26, all done before the epilogue __syncthreads) ----
        if (t + 1 < TT) {
            stage_x(x, bb, t + 1, ty, tx, tid, sg, sb, xpatch);
#pragma unroll
            for (int k = 0; k < 3; k++) {
                async_copy16(gwb + (size_t)k * 16384, &wbuf[k * 8192 + w * 1024]);
                async_copy16(gwb + (size_t)k * 16384 + 1024, &wbuf[k * 8192 + w * 1024 + 512]);
            }
        }
    }
}

extern "C" void kernel_launch(void* const* d_in, const int* in_sizes, int n_in,
                              void* d_out, int out_size, void* d_ws, size_t ws_size,
                              hipStream_t stream) {
    const float* x = (const float*)d_in[0];
    const float* gamma = (const float*)d_in[1];
    const float* beta = (const float*)d_in[2];
    const float* wx = (const float*)d_in[3];
    const float* wh = (const float*)d_in[4];
    const float* bs = (const float*)d_in[5];
    float* out = (float*)d_out;

    // workspace layout (all 16B-aligned)
    char* ws = (char*)d_ws;
    f16* wcat = (f16*)(ws + 16777216);        //    442,368 B (piece-major layout)
    unsigned* flags = (unsigned*)(ws + 17219584);  // 256 x 4 B
    f16* hs = (f16*)(ws + 21413888);          // 35,651,584 B (halo exchange buffer)

    hipMemsetAsync(flags, 0, 256 * 4, stream);
    wprep_kernel<<<864, 256, 0, stream>>>(wx, wh, wcat);

    // Regular launch: 256 blocks x 512 threads x 139.6 KB LDS = exactly 1 block/CU by
    // capacity -> all blocks resident at dispatch; the flags protocol needs nothing more.
    fused_kernel<<<256, 512, 0, stream>>>(x, gamma, beta, wcat, bs, hs, out, flags);
}